// Round 14
// baseline (352.169 us; speedup 1.0000x reference)
//
#include <hip/hip_runtime.h>

typedef __attribute__((ext_vector_type(8))) __bf16 bf16x8;
typedef __attribute__((ext_vector_type(4))) __bf16 bf16x4;
typedef __attribute__((ext_vector_type(4))) float f32x4;

__device__ __forceinline__ bf16x8 zero8() {
  bf16x8 z;
#pragma unroll
  for (int i = 0; i < 8; ++i) z[i] = (__bf16)0.f;
  return z;
}

__device__ __forceinline__ float wave_sum(float v) {
#pragma unroll
  for (int off = 1; off < 64; off <<= 1) v += __shfl_xor(v, off);
  return v;
}

__device__ __forceinline__ void gll(const __bf16* g, __bf16* l) {
  __builtin_amdgcn_global_load_lds(
      (const __attribute__((address_space(1))) void*)g,
      (__attribute__((address_space(3))) void*)l, 16, 0, 0);
}

// ------- K0: f32 -> bf16 conversion of all four weight mats; zeroes kmax -------
__global__ __launch_bounds__(256) void k_cvt4(const float* __restrict__ a,
    const float* __restrict__ b, const float* __restrict__ c, const float* __restrict__ d,
    __bf16* __restrict__ oa, __bf16* __restrict__ ob, __bf16* __restrict__ oc,
    __bf16* __restrict__ od, float* __restrict__ kmax) {
  const int i = blockIdx.x * 256 + threadIdx.x;
  if (blockIdx.x == 0 && threadIdx.x < 32) kmax[threadIdx.x] = 0.f;
  const float* src; __bf16* dst; int off;
  if (i < 442368)      { src = a; dst = oa; off = i; }
  else if (i < 589824) { src = b; dst = ob; off = i - 442368; }
  else if (i < 663552) { src = c; dst = oc; off = i - 589824; }
  else if (i < 737280) { src = d; dst = od; off = i - 663552; }
  else return;
  const f32x4 v = ((const f32x4*)src)[off];
  bf16x4 o;
#pragma unroll
  for (int e = 0; e < 4; ++e) o[e] = (__bf16)v[e];
  ((bf16x4*)dst)[off] = o;
}

// ---------------- K1: tam = sigmoid(sal_w . glb + sal_b), per pixel ----------------
__global__ __launch_bounds__(256) void k_tam(const float* __restrict__ x,
    const float* __restrict__ sal_w, const float* __restrict__ sal_b,
    float* __restrict__ tam) {
  const int lane = threadIdx.x & 63, w = threadIdx.x >> 6;
  const int pix = blockIdx.x * 64 + lane;
  const float* g = x + (size_t)4 * 384 * 9216;
  float acc = 0.f;
  for (int c = w * 96; c < w * 96 + 96; ++c)
    acc += sal_w[c] * g[(size_t)c * 9216 + pix];
  __shared__ float part[4][64];
  part[w][lane] = acc;
  __syncthreads();
  if (w == 0) {
    float v = part[0][lane] + part[1][lane] + part[2][lane] + part[3][lane] + sal_b[0];
    tam[pix] = 1.f / (1.f + __expf(-v));
  }
}

// ------- K2: Q[n][l][c] = x[n][c][l] * tam(quadrant-upsampled)  (transpose) -------
__global__ __launch_bounds__(256) void k_locscale(const float* __restrict__ x,
    const float* __restrict__ tam, __bf16* __restrict__ Q) {
  const int n = blockIdx.y;
  const int l0 = blockIdx.x * 64;
  const int tid = threadIdx.x;
  __shared__ float tile[64][69];
  const size_t bx = (size_t)n * 384 * 9216;
  const int a = n >> 1, b = n & 1;
  for (int c0 = 0; c0 < 384; c0 += 64) {
    if (c0) __syncthreads();
#pragma unroll
    for (int pass = 0; pass < 4; ++pass) {
      int cc = pass * 16 + (tid >> 4);
      int ll = (tid & 15) * 4;
      f32x4 v = *(const f32x4*)&x[bx + (size_t)(c0 + cc) * 9216 + l0 + ll];
#pragma unroll
      for (int e = 0; e < 4; ++e) tile[cc][ll + e] = v[e];
    }
    __syncthreads();
    const int ll = tid >> 2, c1 = (tid & 3) * 16;
    const int l = l0 + ll, i = l / 96, j = l % 96;
    const float tv = tam[(a * 48 + (i >> 1)) * 96 + b * 48 + (j >> 1)];
    const size_t orow = ((size_t)n * 9216 + l) * 384 + c0 + c1;
#pragma unroll
    for (int cc = 0; cc < 16; ++cc)
      Q[orow + cc] = (__bf16)(tile[c1 + cc][ll] * tv);
  }
}

// ---------------- K3: pools from quadrant n of glb -> KV[n][768][384] ----------------
__global__ __launch_bounds__(64) void k_pool(const float* __restrict__ x,
    __bf16* __restrict__ KV) {
  const int c = blockIdx.x, n = blockIdx.y;
  const int a = n >> 1, b = n & 1;
  const float* g = x + (size_t)(4 * 384 + c) * 9216;
  __shared__ float quad[48][48];
  const int t = threadIdx.x;
  for (int k = t; k < 2304; k += 64) {
    int i = k / 48, j = k % 48;
    quad[i][j] = g[(a * 48 + i) * 96 + b * 48 + j];
  }
  __syncthreads();
  for (int s = t; s < 768; s += 64) {
    float val = 0.f;
    if (s < 576) {
      int ti = s / 24, tj = s % 24;
#pragma unroll
      for (int di = 0; di < 2; ++di)
#pragma unroll
        for (int dj = 0; dj < 2; ++dj) val += quad[ti * 2 + di][tj * 2 + dj];
      val *= 0.25f;
    } else if (s < 720) {
      int q = s - 576; int ti = q / 12, tj = q % 12;
      for (int di = 0; di < 4; ++di)
        for (int dj = 0; dj < 4; ++dj) val += quad[ti * 4 + di][tj * 4 + dj];
      val *= (1.f / 16.f);
    } else if (s < 756) {
      int q = s - 720; int ti = q / 6, tj = q % 6;
      for (int di = 0; di < 8; ++di)
        for (int dj = 0; dj < 8; ++dj) val += quad[ti * 8 + di][tj * 8 + dj];
      val *= (1.f / 64.f);
    }
    KV[((size_t)n * 768 + s) * 384 + c] = (__bf16)val;
  }
}

// ------------- Generic MFMA GEMM (128x128 tile, 4 waves) -------------
template <int GELU>
__global__ __launch_bounds__(256) void k_gemm(const __bf16* __restrict__ A,
    const __bf16* __restrict__ B, const float* __restrict__ bias,
    __bf16* __restrict__ C, int K, long sA, long sB, long sBias, long sC,
    float scale) {
  const int z = blockIdx.z;
  A += (size_t)z * sA; B += (size_t)z * sB; bias += (size_t)z * sBias; C += (size_t)z * sC;
  const int m0 = blockIdx.y * 128, n0 = blockIdx.x * 128;
  const int N = gridDim.x * 128;
  __shared__ __bf16 As[128 * 64], Bs[128 * 64];
  const int tid = threadIdx.x, lane = tid & 63, w = tid >> 6;
  const int wm = w >> 1, wn = w & 1;
  const int li = lane & 15, gq = lane >> 4;
  const int lrow = lane >> 3, lcol = (lane & 7) * 8;
  f32x4 acc[4][4] = {};
  const int nk = K >> 6;
  for (int kt = 0; kt < nk; ++kt) {
    const int k0 = kt * 64;
#pragma unroll
    for (int i = 0; i < 4; ++i) {
      const int r0 = w * 32 + i * 8;
      gll(A + (size_t)(m0 + r0 + lrow) * K + k0 + lcol, &As[r0 * 64]);
      gll(B + (size_t)(n0 + r0 + lrow) * K + k0 + lcol, &Bs[r0 * 64]);
    }
    __syncthreads();
#pragma unroll
    for (int kk = 0; kk < 2; ++kk) {
      bf16x8 af[4], bfr[4];
#pragma unroll
      for (int f = 0; f < 4; ++f) {
        af[f] = *(const bf16x8*)&As[(wm * 64 + f * 16 + li) * 64 + kk * 32 + gq * 8];
        bfr[f] = *(const bf16x8*)&Bs[(wn * 64 + f * 16 + li) * 64 + kk * 32 + gq * 8];
      }
#pragma unroll
      for (int fm = 0; fm < 4; ++fm)
#pragma unroll
        for (int fn = 0; fn < 4; ++fn)
          acc[fm][fn] = __builtin_amdgcn_mfma_f32_16x16x32_bf16(af[fm], bfr[fn], acc[fm][fn], 0, 0, 0);
    }
    __syncthreads();
  }
  float bv[4];
#pragma unroll
  for (int fn = 0; fn < 4; ++fn) bv[fn] = bias[n0 + wn * 64 + fn * 16 + li];
#pragma unroll
  for (int fm = 0; fm < 4; ++fm) {
    const int row = m0 + wm * 64 + fm * 16 + gq * 4;
#pragma unroll
    for (int fn = 0; fn < 4; ++fn) {
      const int col = n0 + wn * 64 + fn * 16 + li;
#pragma unroll
      for (int r = 0; r < 4; ++r) {
        float v = (acc[fm][fn][r] + bv[fn]) * scale;
        if (GELU) v = 0.5f * v * (1.f + erff(v * 0.70710678118654752f));
        C[(size_t)(row + r) * N + col] = (__bf16)v;
      }
    }
  }
}

// ------------- K_gemm256: 256x128 tile, 8 waves (2 col x 4 row wave grid) -------------
template <int GELU>
__global__ __launch_bounds__(512) void k_gemm256(const __bf16* __restrict__ A,
    const __bf16* __restrict__ B, const float* __restrict__ bias,
    __bf16* __restrict__ C, int K, long sA, long sB, long sBias, long sC,
    float scale) {
  const int z = blockIdx.z;
  A += (size_t)z * sA; B += (size_t)z * sB; bias += (size_t)z * sBias; C += (size_t)z * sC;
  const int m0 = blockIdx.y * 256, n0 = blockIdx.x * 128;
  const int N = gridDim.x * 128;
  __shared__ __bf16 As[256 * 64], Bs[128 * 64];
  const int tid = threadIdx.x, lane = tid & 63, w = tid >> 6;  // w in 0..7
  const int wm = w >> 1, wn = w & 1;                           // wm 0..3, wn 0..1
  const int li = lane & 15, gq = lane >> 4;
  const int lrow = lane >> 3, lcol = (lane & 7) * 8;
  f32x4 acc[4][4] = {};
  const int nk = K >> 6;
  for (int kt = 0; kt < nk; ++kt) {
    const int k0 = kt * 64;
#pragma unroll
    for (int i = 0; i < 4; ++i) {
      const int r0 = w * 32 + i * 8;
      gll(A + (size_t)(m0 + r0 + lrow) * K + k0 + lcol, &As[r0 * 64]);
    }
#pragma unroll
    for (int j = 0; j < 2; ++j) {
      const int r0 = w * 16 + j * 8;
      gll(B + (size_t)(n0 + r0 + lrow) * K + k0 + lcol, &Bs[r0 * 64]);
    }
    __syncthreads();
#pragma unroll
    for (int kk = 0; kk < 2; ++kk) {
      bf16x8 af[4], bfr[4];
#pragma unroll
      for (int f = 0; f < 4; ++f) {
        af[f] = *(const bf16x8*)&As[(wm * 64 + f * 16 + li) * 64 + kk * 32 + gq * 8];
        bfr[f] = *(const bf16x8*)&Bs[(wn * 64 + f * 16 + li) * 64 + kk * 32 + gq * 8];
      }
#pragma unroll
      for (int fm = 0; fm < 4; ++fm)
#pragma unroll
        for (int fn = 0; fn < 4; ++fn)
          acc[fm][fn] = __builtin_amdgcn_mfma_f32_16x16x32_bf16(af[fm], bfr[fn], acc[fm][fn], 0, 0, 0);
    }
    __syncthreads();
  }
  float bv[4];
#pragma unroll
  for (int fn = 0; fn < 4; ++fn) bv[fn] = bias[n0 + wn * 64 + fn * 16 + li];
#pragma unroll
  for (int fm = 0; fm < 4; ++fm) {
    const int row = m0 + wm * 64 + fm * 16 + gq * 4;
#pragma unroll
    for (int fn = 0; fn < 4; ++fn) {
      const int col = n0 + wn * 64 + fn * 16 + li;
#pragma unroll
      for (int r = 0; r < 4; ++r) {
        float v = (acc[fm][fn][r] + bv[fn]) * scale;
        if (GELU) v = 0.5f * v * (1.f + erff(v * 0.70710678118654752f));
        C[(size_t)(row + r) * N + col] = (__bf16)v;
      }
    }
  }
}

// ---- K4: V transpose KVH[n][s][384+h*48+d] -> VT[nh][d][s]; also kmax via atomicMax ----
__global__ __launch_bounds__(256) void k_vt(const __bf16* __restrict__ KVH,
    __bf16* __restrict__ VT, float* __restrict__ kmax) {
  const int nh = blockIdx.y, n = nh >> 3, h = nh & 7;
  const int s0 = blockIdx.x * 256;
  __shared__ __bf16 tile[48][264];
  const int tid = threadIdx.x;
  const size_t bv = (size_t)n * 768 * 768 + 384 + h * 48;
#pragma unroll
  for (int it = 0; it < 6; ++it) {
    const int task = tid + it * 256;
    const int s = task / 6, ch = task % 6;
    bf16x8 v = *(const bf16x8*)&KVH[bv + (size_t)(s0 + s) * 768 + ch * 8];
#pragma unroll
    for (int e = 0; e < 8; ++e) tile[ch * 8 + e][s] = v[e];
  }
  {
    const int s = s0 + tid;
    float a2 = 0.f;
    if (s < 756) {
      const size_t bk = (size_t)n * 768 * 768 + h * 48;
#pragma unroll
      for (int ch = 0; ch < 6; ++ch) {
        bf16x8 kv = *(const bf16x8*)&KVH[bk + (size_t)s * 768 + ch * 8];
#pragma unroll
        for (int e = 0; e < 8; ++e) { const float f = (float)kv[e]; a2 += f * f; }
      }
    }
#pragma unroll
    for (int off = 1; off < 64; off <<= 1) a2 = fmaxf(a2, __shfl_xor(a2, off));
    if ((tid & 63) == 0)
      atomicMax((unsigned*)&kmax[nh], __float_as_uint(a2));  // floats >= 0
  }
  __syncthreads();
#pragma unroll
  for (int it = 0; it < 6; ++it) {
    const int task = tid + it * 256;
    const int d = task >> 5, so = (task & 31) * 8;
    bf16x8 v2 = *(const bf16x8*)&tile[d][so];
    *(bf16x8*)&VT[((size_t)nh * 48 + d) * 768 + s0 + so] = v2;
  }
}

// ------------- K5: fused attention, 16 waves / 256 queries per block -------------
// QH pre-scaled by (1/sqrt(48))*log2(e); fixed shift m_fix = ||q||*max||K||.
__global__ __launch_bounds__(1024) void k_attn(const __bf16* __restrict__ QH,
    const __bf16* __restrict__ KVH, const __bf16* __restrict__ VT,
    const float* __restrict__ kmax, __bf16* __restrict__ AO) {
  const int nh = blockIdx.y, n = nh >> 3, h = nh & 7;
  const int l0 = blockIdx.x * 256;
  const int tid = threadIdx.x, lane = tid & 63, w = tid >> 6;  // w in 0..15
  const int gq = lane >> 4, li = lane & 15;
  const int l0w = l0 + w * 16;
  __shared__ __bf16 Ks[64 * 64];      // K tile [s][d], XOR-swizzled cols
  __shared__ __bf16 Vs[48 * 64];      // V^T tile [d][s], XOR-swizzled cols
  __shared__ __bf16 P[16][16 * 68];   // per-wave P [l][s]
  __bf16* Pw = &P[w][0];
  const size_t bq = ((size_t)n * 9216) * 384 + h * 48;
  const size_t bk = (size_t)n * 768 * 768 + h * 48;   // K rows in KVH, stride 768
  const __bf16* vt = VT + (size_t)nh * 48 * 768;
  const int scol = 8 * ((lane & 7) ^ (lane >> 3));    // pre-swizzled source col
  const int rsw = 8 * (li & 7);                       // read-side swizzle
  bf16x8 qf[2];
#pragma unroll
  for (int kk = 0; kk < 2; ++kk) {
    const int d0 = kk * 32 + gq * 8;
    qf[kk] = (d0 < 48) ? *(const bf16x8*)&QH[bq + (size_t)(l0w + li) * 384 + d0] : zero8();
  }
  float q2 = 0.f;
#pragma unroll
  for (int kk = 0; kk < 2; ++kk)
#pragma unroll
    for (int e = 0; e < 8; ++e) { const float f = (float)qf[kk][e]; q2 += f * f; }
  q2 += __shfl_xor(q2, 16);
  q2 += __shfl_xor(q2, 32);
  const float m_fix = sqrtf(q2 * kmax[nh]);
  float l_run = 0.f;
  f32x4 o[3] = {};
  for (int t = 0; t < 12; ++t) {
    const int s0 = t * 64;
    __syncthreads();  // prior tile's LDS reads complete before restage
    if (w < 8) {      // K tile: waves 0..7 stage 8 rows each
      const int rbase = w * 8;
      gll(KVH + bk + (size_t)(s0 + rbase + (lane >> 3)) * 768 + scol, &Ks[rbase * 64]);
    } else if (w < 14) {  // V^T tile: waves 8..13 stage 8 rows each
      const int rbase = (w - 8) * 8;
      gll(vt + (size_t)(rbase + (lane >> 3)) * 768 + s0 + scol, &Vs[rbase * 64]);
    }
    __syncthreads();  // staged data visible (barrier drains vmcnt)
    f32x4 sc[4];
#pragma unroll
    for (int st = 0; st < 4; ++st) {
      f32x4 a = {};
#pragma unroll
      for (int kk = 0; kk < 2; ++kk) {
        const bf16x8 kf = *(const bf16x8*)&Ks[(st * 16 + li) * 64 + ((kk * 32 + gq * 8) ^ rsw)];
        a = __builtin_amdgcn_mfma_f32_16x16x32_bf16(kf, qf[kk], a, 0, 0, 0);
      }
      sc[st] = a;
    }
    if (t == 11) {  // mask s >= 756 (only last tile)
#pragma unroll
      for (int st = 0; st < 4; ++st)
#pragma unroll
        for (int r = 0; r < 4; ++r)
          if (st * 16 + gq * 4 + r >= 52) sc[st][r] = -1e30f;
    }
#pragma unroll
    for (int st = 0; st < 4; ++st)
#pragma unroll
      for (int r = 0; r < 4; ++r) {
        const float p = __builtin_amdgcn_exp2f(sc[st][r] - m_fix);
        sc[st][r] = p;
        l_run += p;
      }
#pragma unroll
    for (int st = 0; st < 4; ++st) {
      bf16x4 pk;
#pragma unroll
      for (int r = 0; r < 4; ++r) pk[r] = (__bf16)sc[st][r];
      *(bf16x4*)&Pw[li * 68 + st * 16 + gq * 4] = pk;
    }
#pragma unroll
    for (int kk = 0; kk < 2; ++kk) {
      const bf16x4 plo = *(const bf16x4*)&Pw[li * 68 + kk * 32 + gq * 8];
      const bf16x4 phi = *(const bf16x4*)&Pw[li * 68 + kk * 32 + gq * 8 + 4];
      bf16x8 ap;
#pragma unroll
      for (int e = 0; e < 4; ++e) { ap[e] = plo[e]; ap[e + 4] = phi[e]; }
#pragma unroll
      for (int df = 0; df < 3; ++df) {
        const bf16x8 bv = *(const bf16x8*)&Vs[(df * 16 + li) * 64 + ((kk * 32 + gq * 8) ^ rsw)];
        o[df] = __builtin_amdgcn_mfma_f32_16x16x32_bf16(ap, bv, o[df], 0, 0, 0);
      }
    }
  }
  l_run += __shfl_xor(l_run, 16);
  l_run += __shfl_xor(l_run, 32);
  const float inv = 1.f / l_run;
  float ir[4];
#pragma unroll
  for (int r = 0; r < 4; ++r) ir[r] = __shfl(inv, gq * 4 + r, 16);
#pragma unroll
  for (int df = 0; df < 3; ++df)
#pragma unroll
    for (int r = 0; r < 4; ++r)
      AO[bq + (size_t)(l0w + gq * 4 + r) * 384 + df * 16 + li] = (__bf16)(o[df][r] * ir[r]);
}

// ---------------- K7: LN1 over c of (loc + attn_proj); writes in place ----------------
__global__ __launch_bounds__(256) void k_ln1(const __bf16* Q,
    const __bf16* P, const float* g1, const float* b1, __bf16* S1) {
  const size_t row = (size_t)blockIdx.x * 4 + (threadIdx.x >> 6);
  const int lane = threadIdx.x & 63;
  const __bf16* q = Q + row * 384;
  const __bf16* p = P + row * 384;
  float v[6], s = 0.f;
#pragma unroll
  for (int e = 0; e < 6; ++e) {
    const int c = e * 64 + lane;
    v[e] = (float)q[c] + (float)p[c];
    s += v[e];
  }
  s = wave_sum(s);
  const float mean = s * (1.f / 384.f);
  float var = 0.f;
#pragma unroll
  for (int e = 0; e < 6; ++e) { const float d = v[e] - mean; var += d * d; }
  var = wave_sum(var) * (1.f / 384.f);
  const float rstd = rsqrtf(var + 1e-5f);
  __bf16* o = S1 + row * 384;
#pragma unroll
  for (int e = 0; e < 6; ++e) {
    const int c = e * 64 + lane;
    o[c] = (__bf16)(((v[e] - mean) * rstd) * g1[c] + b1[c]);
  }
}

// ---- K10: LN2 of (S1 + FF) -> transposed f32 store; fused glb-quadrant update ----
__global__ __launch_bounds__(256) void k_ln2(const __bf16* __restrict__ S1,
    const __bf16* __restrict__ FF, const float* __restrict__ g2,
    const float* __restrict__ b2, const float* __restrict__ x,
    float* __restrict__ out) {
  const int n = blockIdx.y, l0 = blockIdx.x * 64;
  const int tid = threadIdx.x, w = tid >> 6, lane = tid & 63;
  __shared__ __bf16 tile[64][390];
  for (int rr = 0; rr < 16; ++rr) {
    const int ll = w * 16 + rr;
    const size_t row = ((size_t)n * 9216 + l0 + ll) * 384;
    float v[6], s = 0.f;
#pragma unroll
    for (int e = 0; e < 6; ++e) {
      const int c = e * 64 + lane;
      v[e] = (float)S1[row + c] + (float)FF[row + c];
      s += v[e];
    }
    s = wave_sum(s);
    const float mean = s * (1.f / 384.f);
    float var = 0.f;
#pragma unroll
    for (int e = 0; e < 6; ++e) { const float d = v[e] - mean; var += d * d; }
    var = wave_sum(var) * (1.f / 384.f);
    const float rstd = rsqrtf(var + 1e-5f);
#pragma unroll
    for (int e = 0; e < 6; ++e) {
      const int c = e * 64 + lane;
      tile[ll][c] = (__bf16)(((v[e] - mean) * rstd) * g2[c] + b2[c]);
    }
  }
  __syncthreads();
  const int l = l0 + lane, i = l / 96, j = l % 96;
  const int a = n >> 1, b = n & 1;
  const bool doGlb = ((i | j) & 1) == 0;
  const int gl = (a * 48 + (i >> 1)) * 96 + b * 48 + (j >> 1);
  for (int it = 0; it < 96; ++it) {
    const int c = it * 4 + w;
    const float v = (float)tile[lane][c];
    out[((size_t)n * 384 + c) * 9216 + l0 + lane] = v;
    if (doGlb) {
      const size_t gidx = (size_t)(4 * 384 + c) * 9216 + gl;
      out[gidx] = x[gidx] + v;
    }
  }
}

extern "C" void kernel_launch(void* const* d_in, const int* in_sizes, int n_in,
                              void* d_out, int out_size, void* d_ws, size_t ws_size,
                              hipStream_t stream) {
  const float* x     = (const float*)d_in[0];
  const float* sal_w = (const float*)d_in[1];
  const float* sal_b = (const float*)d_in[2];
  const float* aiw   = (const float*)d_in[3];
  const float* aib   = (const float*)d_in[4];
  const float* aow   = (const float*)d_in[5];
  const float* aob   = (const float*)d_in[6];
  const float* w3    = (const float*)d_in[7];
  const float* b3    = (const float*)d_in[8];
  const float* w4    = (const float*)d_in[9];
  const float* b4    = (const float*)d_in[10];
  const float* g1    = (const float*)d_in[11];
  const float* be1   = (const float*)d_in[12];
  const float* g2    = (const float*)d_in[13];
  const float* be2   = (const float*)d_in[14];
  float* out = (float*)d_out;
  char* ws = (char*)d_ws;

  // ws layout (total 69,636,096 B)
  float*  tam  = (float*)(ws + 0);                //     36,864 B
  __bf16* aiwB = (__bf16*)(ws + 36864);           //  3,538,944 B
  __bf16* aowB = (__bf16*)(ws + 3575808);         //  1,179,648 B
  __bf16* w3B  = (__bf16*)(ws + 4755456);         //    589,824 B
  __bf16* w4B  = (__bf16*)(ws + 5345280);         //    589,824 B
  __bf16* KV   = (__bf16*)(ws + 5935104);         //  2,359,296 B (pools; later VTg)
  __bf16* KVH  = (__bf16*)(ws + 8294400);         //  4,718,592 B (K|V merged [4][768][768])
  __bf16* Q    = (__bf16*)(ws + 13012992);        // 28,311,552 B  loc_scaled -> S1 (in place)
  __bf16* QHb  = (__bf16*)(ws + 41324544);        // 28,311,552 B  qproj -> P -> FF
  __bf16* VTg = KV;               // V^T [32][48][768] reuses pools slot
  __bf16* AO  = (__bf16*)d_out;   // attn out [4][9216][384] bf16 (28.3 MB of 70.8)
  __bf16* HID = (__bf16*)d_out;   // FFN hidden 36864x768 bf16 (56.6 MB, AO dead by then)
  float* kmax = (float*)((char*)d_out + 70778368);  // last 512 B of d_out
  __bf16* P   = QHb;
  __bf16* S1  = Q;
  __bf16* FF  = QHb;

  const float qscale = 0.20823509f;  // (1/sqrt(48)) * log2(e)

  k_cvt4<<<2880, 256, 0, stream>>>(aiw, aow, w3, w4, aiwB, aowB, w3B, w4B, kmax);

  k_tam<<<144, 256, 0, stream>>>(x, sal_w, sal_b, tam);
  k_locscale<<<dim3(144, 4), 256, 0, stream>>>(x, tam, Q);
  k_pool<<<dim3(384, 4), 64, 0, stream>>>(x, KV);

  // merged K+V projection: KVH[768 s][768] = K | V
  k_gemm<0><<<dim3(6, 6, 4), 256, 0, stream>>>(KV, aiwB + 384 * 384, aib + 384, KVH,
      384, 768L * 384, 1152L * 384, 1152L, 768L * 768, 1.f);
  // Q projection (pre-scaled for log2-domain softmax), 256-row tiles
  k_gemm256<0><<<dim3(3, 36, 4), 512, 0, stream>>>(Q, aiwB, aib, QHb,
      384, 9216L * 384, 1152L * 384, 1152L, 9216L * 384, qscale);

  // V transpose + kmax (fused)
  k_vt<<<dim3(3, 32), 256, 0, stream>>>(KVH, VTg, kmax);

  k_attn<<<dim3(36, 32), 1024, 0, stream>>>(QHb, KVH, VTg, kmax, AO);

  // out-projection: AO x aow^T -> P (QHb region; qproj dead), 256-row tiles
  k_gemm256<0><<<dim3(3, 36, 4), 512, 0, stream>>>(AO, aowB, aob, P,
      384, 9216L * 384, 384L * 384, 384L, 9216L * 384, 1.f);

  // LN1 in place into Q region
  k_ln1<<<9216, 256, 0, stream>>>(Q, P, g1, be1, S1);

  // FFN single pass: HID (d_out, AO dead) <- GELU(S1 w3^T); FF (QHb) <- HID w4^T
  k_gemm256<1><<<dim3(6, 144, 1), 512, 0, stream>>>(S1, w3B, b3, HID,
      384, 0, 0, 0, 0, 1.f);
  k_gemm256<0><<<dim3(3, 144, 1), 512, 0, stream>>>(HID, w4B, b4, FF,
      768, 0, 0, 0, 0, 1.f);

  // LN2 + transposed f32 store + fused glb update
  k_ln2<<<dim3(144, 4), 256, 0, stream>>>(S1, FF, g2, be2, x, out);
}

// Round 15
// 325.118 us; speedup vs baseline: 1.0832x; 1.0832x over previous
//
#include <hip/hip_runtime.h>

typedef __attribute__((ext_vector_type(8))) __bf16 bf16x8;
typedef __attribute__((ext_vector_type(4))) __bf16 bf16x4;
typedef __attribute__((ext_vector_type(4))) float f32x4;

__device__ __forceinline__ bf16x8 zero8() {
  bf16x8 z;
#pragma unroll
  for (int i = 0; i < 8; ++i) z[i] = (__bf16)0.f;
  return z;
}

__device__ __forceinline__ float wave_sum(float v) {
#pragma unroll
  for (int off = 1; off < 64; off <<= 1) v += __shfl_xor(v, off);
  return v;
}

__device__ __forceinline__ void gll(const __bf16* g, __bf16* l) {
  __builtin_amdgcn_global_load_lds(
      (const __attribute__((address_space(1))) void*)g,
      (__attribute__((address_space(3))) void*)l, 16, 0, 0);
}

// ------- K0: f32 -> bf16 conversion of all four weight mats; zeroes kmax -------
__global__ __launch_bounds__(256) void k_cvt4(const float* __restrict__ a,
    const float* __restrict__ b, const float* __restrict__ c, const float* __restrict__ d,
    __bf16* __restrict__ oa, __bf16* __restrict__ ob, __bf16* __restrict__ oc,
    __bf16* __restrict__ od, float* __restrict__ kmax) {
  const int i = blockIdx.x * 256 + threadIdx.x;
  if (blockIdx.x == 0 && threadIdx.x < 32) kmax[threadIdx.x] = 0.f;
  const float* src; __bf16* dst; int off;
  if (i < 442368)      { src = a; dst = oa; off = i; }
  else if (i < 589824) { src = b; dst = ob; off = i - 442368; }
  else if (i < 663552) { src = c; dst = oc; off = i - 589824; }
  else if (i < 737280) { src = d; dst = od; off = i - 663552; }
  else return;
  const f32x4 v = ((const f32x4*)src)[off];
  bf16x4 o;
#pragma unroll
  for (int e = 0; e < 4; ++e) o[e] = (__bf16)v[e];
  ((bf16x4*)dst)[off] = o;
}

// ---------------- K1: tam = sigmoid(sal_w . glb + sal_b), per pixel ----------------
__global__ __launch_bounds__(256) void k_tam(const float* __restrict__ x,
    const float* __restrict__ sal_w, const float* __restrict__ sal_b,
    float* __restrict__ tam) {
  const int lane = threadIdx.x & 63, w = threadIdx.x >> 6;
  const int pix = blockIdx.x * 64 + lane;
  const float* g = x + (size_t)4 * 384 * 9216;
  float acc = 0.f;
  for (int c = w * 96; c < w * 96 + 96; ++c)
    acc += sal_w[c] * g[(size_t)c * 9216 + pix];
  __shared__ float part[4][64];
  part[w][lane] = acc;
  __syncthreads();
  if (w == 0) {
    float v = part[0][lane] + part[1][lane] + part[2][lane] + part[3][lane] + sal_b[0];
    tam[pix] = 1.f / (1.f + __expf(-v));
  }
}

// ------- K2: Q[n][l][c] = x[n][c][l] * tam(quadrant-upsampled)  (transpose) -------
__global__ __launch_bounds__(256) void k_locscale(const float* __restrict__ x,
    const float* __restrict__ tam, __bf16* __restrict__ Q) {
  const int n = blockIdx.y;
  const int l0 = blockIdx.x * 64;
  const int tid = threadIdx.x;
  __shared__ float tile[64][69];
  const size_t bx = (size_t)n * 384 * 9216;
  const int a = n >> 1, b = n & 1;
  for (int c0 = 0; c0 < 384; c0 += 64) {
    if (c0) __syncthreads();
#pragma unroll
    for (int pass = 0; pass < 4; ++pass) {
      int cc = pass * 16 + (tid >> 4);
      int ll = (tid & 15) * 4;
      f32x4 v = *(const f32x4*)&x[bx + (size_t)(c0 + cc) * 9216 + l0 + ll];
#pragma unroll
      for (int e = 0; e < 4; ++e) tile[cc][ll + e] = v[e];
    }
    __syncthreads();
    const int ll = tid >> 2, c1 = (tid & 3) * 16;
    const int l = l0 + ll, i = l / 96, j = l % 96;
    const float tv = tam[(a * 48 + (i >> 1)) * 96 + b * 48 + (j >> 1)];
    const size_t orow = ((size_t)n * 9216 + l) * 384 + c0 + c1;
#pragma unroll
    for (int cc = 0; cc < 16; ++cc)
      Q[orow + cc] = (__bf16)(tile[c1 + cc][ll] * tv);
  }
}

// ---------------- K3: pools from quadrant n of glb -> KV[n][768][384] ----------------
__global__ __launch_bounds__(64) void k_pool(const float* __restrict__ x,
    __bf16* __restrict__ KV) {
  const int c = blockIdx.x, n = blockIdx.y;
  const int a = n >> 1, b = n & 1;
  const float* g = x + (size_t)(4 * 384 + c) * 9216;
  __shared__ float quad[48][48];
  const int t = threadIdx.x;
  for (int k = t; k < 2304; k += 64) {
    int i = k / 48, j = k % 48;
    quad[i][j] = g[(a * 48 + i) * 96 + b * 48 + j];
  }
  __syncthreads();
  for (int s = t; s < 768; s += 64) {
    float val = 0.f;
    if (s < 576) {
      int ti = s / 24, tj = s % 24;
#pragma unroll
      for (int di = 0; di < 2; ++di)
#pragma unroll
        for (int dj = 0; dj < 2; ++dj) val += quad[ti * 2 + di][tj * 2 + dj];
      val *= 0.25f;
    } else if (s < 720) {
      int q = s - 576; int ti = q / 12, tj = q % 12;
      for (int di = 0; di < 4; ++di)
        for (int dj = 0; dj < 4; ++dj) val += quad[ti * 4 + di][tj * 4 + dj];
      val *= (1.f / 16.f);
    } else if (s < 756) {
      int q = s - 720; int ti = q / 6, tj = q % 6;
      for (int di = 0; di < 8; ++di)
        for (int dj = 0; dj < 8; ++dj) val += quad[ti * 8 + di][tj * 8 + dj];
      val *= (1.f / 64.f);
    }
    KV[((size_t)n * 768 + s) * 384 + c] = (__bf16)val;
  }
}

// ------------- Generic MFMA GEMM (128x128 tile, 4 waves) -------------
template <int GELU>
__global__ __launch_bounds__(256) void k_gemm(const __bf16* __restrict__ A,
    const __bf16* __restrict__ B, const float* __restrict__ bias,
    __bf16* __restrict__ C, int K, long sA, long sB, long sBias, long sC,
    float scale) {
  const int z = blockIdx.z;
  A += (size_t)z * sA; B += (size_t)z * sB; bias += (size_t)z * sBias; C += (size_t)z * sC;
  const int m0 = blockIdx.y * 128, n0 = blockIdx.x * 128;
  const int N = gridDim.x * 128;
  __shared__ __bf16 As[128 * 64], Bs[128 * 64];
  const int tid = threadIdx.x, lane = tid & 63, w = tid >> 6;
  const int wm = w >> 1, wn = w & 1;
  const int li = lane & 15, gq = lane >> 4;
  const int lrow = lane >> 3, lcol = (lane & 7) * 8;
  f32x4 acc[4][4] = {};
  const int nk = K >> 6;
  for (int kt = 0; kt < nk; ++kt) {
    const int k0 = kt * 64;
#pragma unroll
    for (int i = 0; i < 4; ++i) {
      const int r0 = w * 32 + i * 8;
      gll(A + (size_t)(m0 + r0 + lrow) * K + k0 + lcol, &As[r0 * 64]);
      gll(B + (size_t)(n0 + r0 + lrow) * K + k0 + lcol, &Bs[r0 * 64]);
    }
    __syncthreads();
#pragma unroll
    for (int kk = 0; kk < 2; ++kk) {
      bf16x8 af[4], bfr[4];
#pragma unroll
      for (int f = 0; f < 4; ++f) {
        af[f] = *(const bf16x8*)&As[(wm * 64 + f * 16 + li) * 64 + kk * 32 + gq * 8];
        bfr[f] = *(const bf16x8*)&Bs[(wn * 64 + f * 16 + li) * 64 + kk * 32 + gq * 8];
      }
#pragma unroll
      for (int fm = 0; fm < 4; ++fm)
#pragma unroll
        for (int fn = 0; fn < 4; ++fn)
          acc[fm][fn] = __builtin_amdgcn_mfma_f32_16x16x32_bf16(af[fm], bfr[fn], acc[fm][fn], 0, 0, 0);
    }
    __syncthreads();
  }
  float bv[4];
#pragma unroll
  for (int fn = 0; fn < 4; ++fn) bv[fn] = bias[n0 + wn * 64 + fn * 16 + li];
#pragma unroll
  for (int fm = 0; fm < 4; ++fm) {
    const int row = m0 + wm * 64 + fm * 16 + gq * 4;
#pragma unroll
    for (int fn = 0; fn < 4; ++fn) {
      const int col = n0 + wn * 64 + fn * 16 + li;
#pragma unroll
      for (int r = 0; r < 4; ++r) {
        float v = (acc[fm][fn][r] + bv[fn]) * scale;
        if (GELU) v = 0.5f * v * (1.f + erff(v * 0.70710678118654752f));
        C[(size_t)(row + r) * N + col] = (__bf16)v;
      }
    }
  }
}

// ------------- K_gemm256: 256x128 tile, 8 waves (2 col x 4 row wave grid) -------------
// Same fragment scheme as k_gemm; +33% staging amortization, half the barriers/output.
template <int GELU>
__global__ __launch_bounds__(512) void k_gemm256(const __bf16* __restrict__ A,
    const __bf16* __restrict__ B, const float* __restrict__ bias,
    __bf16* __restrict__ C, int K, long sA, long sB, long sBias, long sC,
    float scale) {
  const int z = blockIdx.z;
  A += (size_t)z * sA; B += (size_t)z * sB; bias += (size_t)z * sBias; C += (size_t)z * sC;
  const int m0 = blockIdx.y * 256, n0 = blockIdx.x * 128;
  const int N = gridDim.x * 128;
  __shared__ __bf16 As[256 * 64], Bs[128 * 64];
  const int tid = threadIdx.x, lane = tid & 63, w = tid >> 6;  // w in 0..7
  const int wm = w >> 1, wn = w & 1;                           // wm 0..3, wn 0..1
  const int li = lane & 15, gq = lane >> 4;
  const int lrow = lane >> 3, lcol = (lane & 7) * 8;
  f32x4 acc[4][4] = {};
  const int nk = K >> 6;
  for (int kt = 0; kt < nk; ++kt) {
    const int k0 = kt * 64;
#pragma unroll
    for (int i = 0; i < 4; ++i) {  // A: wave w stages rows w*32 .. w*32+31
      const int r0 = w * 32 + i * 8;
      gll(A + (size_t)(m0 + r0 + lrow) * K + k0 + lcol, &As[r0 * 64]);
    }
#pragma unroll
    for (int j = 0; j < 2; ++j) {  // B: wave w stages rows w*16 .. w*16+15
      const int r0 = w * 16 + j * 8;
      gll(B + (size_t)(n0 + r0 + lrow) * K + k0 + lcol, &Bs[r0 * 64]);
    }
    __syncthreads();
#pragma unroll
    for (int kk = 0; kk < 2; ++kk) {
      bf16x8 af[4], bfr[4];
#pragma unroll
      for (int f = 0; f < 4; ++f) {
        af[f] = *(const bf16x8*)&As[(wm * 64 + f * 16 + li) * 64 + kk * 32 + gq * 8];
        bfr[f] = *(const bf16x8*)&Bs[(wn * 64 + f * 16 + li) * 64 + kk * 32 + gq * 8];
      }
#pragma unroll
      for (int fm = 0; fm < 4; ++fm)
#pragma unroll
        for (int fn = 0; fn < 4; ++fn)
          acc[fm][fn] = __builtin_amdgcn_mfma_f32_16x16x32_bf16(af[fm], bfr[fn], acc[fm][fn], 0, 0, 0);
    }
    __syncthreads();
  }
  float bv[4];
#pragma unroll
  for (int fn = 0; fn < 4; ++fn) bv[fn] = bias[n0 + wn * 64 + fn * 16 + li];
#pragma unroll
  for (int fm = 0; fm < 4; ++fm) {
    const int row = m0 + wm * 64 + fm * 16 + gq * 4;
#pragma unroll
    for (int fn = 0; fn < 4; ++fn) {
      const int col = n0 + wn * 64 + fn * 16 + li;
#pragma unroll
      for (int r = 0; r < 4; ++r) {
        float v = (acc[fm][fn][r] + bv[fn]) * scale;
        if (GELU) v = 0.5f * v * (1.f + erff(v * 0.70710678118654752f));
        C[(size_t)(row + r) * N + col] = (__bf16)v;
      }
    }
  }
}

// ---- K4: V transpose KVH[n][s][384+h*48+d] -> VT[nh][d][s]; also kmax via atomicMax ----
__global__ __launch_bounds__(256) void k_vt(const __bf16* __restrict__ KVH,
    __bf16* __restrict__ VT, float* __restrict__ kmax) {
  const int nh = blockIdx.y, n = nh >> 3, h = nh & 7;
  const int s0 = blockIdx.x * 256;
  __shared__ __bf16 tile[48][264];
  const int tid = threadIdx.x;
  const size_t bv = (size_t)n * 768 * 768 + 384 + h * 48;
#pragma unroll
  for (int it = 0; it < 6; ++it) {
    const int task = tid + it * 256;
    const int s = task / 6, ch = task % 6;
    bf16x8 v = *(const bf16x8*)&KVH[bv + (size_t)(s0 + s) * 768 + ch * 8];
#pragma unroll
    for (int e = 0; e < 8; ++e) tile[ch * 8 + e][s] = v[e];
  }
  {
    const int s = s0 + tid;
    float a2 = 0.f;
    if (s < 756) {
      const size_t bk = (size_t)n * 768 * 768 + h * 48;
#pragma unroll
      for (int ch = 0; ch < 6; ++ch) {
        bf16x8 kv = *(const bf16x8*)&KVH[bk + (size_t)s * 768 + ch * 8];
#pragma unroll
        for (int e = 0; e < 8; ++e) { const float f = (float)kv[e]; a2 += f * f; }
      }
    }
#pragma unroll
    for (int off = 1; off < 64; off <<= 1) a2 = fmaxf(a2, __shfl_xor(a2, off));
    if ((tid & 63) == 0)
      atomicMax((unsigned*)&kmax[nh], __float_as_uint(a2));  // floats >= 0
  }
  __syncthreads();
#pragma unroll
  for (int it = 0; it < 6; ++it) {
    const int task = tid + it * 256;
    const int d = task >> 5, so = (task & 31) * 8;
    bf16x8 v2 = *(const bf16x8*)&tile[d][so];
    *(bf16x8*)&VT[((size_t)nh * 48 + d) * 768 + s0 + so] = v2;
  }
}

// ------------- K5: fused attention, 8 waves / 128 queries per block -------------
// QH pre-scaled by (1/sqrt(48))*log2(e); fixed shift m_fix = ||q||*max||K||.
__global__ __launch_bounds__(512) void k_attn(const __bf16* __restrict__ QH,
    const __bf16* __restrict__ KVH, const __bf16* __restrict__ VT,
    const float* __restrict__ kmax, __bf16* __restrict__ AO) {
  const int nh = blockIdx.y, n = nh >> 3, h = nh & 7;
  const int l0 = blockIdx.x * 128;
  const int tid = threadIdx.x, lane = tid & 63, w = tid >> 6;  // w in 0..7
  const int gq = lane >> 4, li = lane & 15;
  const int l0w = l0 + w * 16;
  __shared__ __bf16 Ks[64 * 64];     // K tile [s][d], XOR-swizzled cols
  __shared__ __bf16 Vs[48 * 64];     // V^T tile [d][s], XOR-swizzled cols
  __shared__ __bf16 P[8][16 * 68];   // per-wave P [l][s]
  __bf16* Pw = &P[w][0];
  const size_t bq = ((size_t)n * 9216) * 384 + h * 48;
  const size_t bk = (size_t)n * 768 * 768 + h * 48;   // K rows in KVH, stride 768
  const __bf16* vt = VT + (size_t)nh * 48 * 768;
  const int scol = 8 * ((lane & 7) ^ (lane >> 3));    // pre-swizzled source col
  const int rsw = 8 * (li & 7);                       // read-side swizzle
  bf16x8 qf[2];
#pragma unroll
  for (int kk = 0; kk < 2; ++kk) {
    const int d0 = kk * 32 + gq * 8;
    qf[kk] = (d0 < 48) ? *(const bf16x8*)&QH[bq + (size_t)(l0w + li) * 384 + d0] : zero8();
  }
  float q2 = 0.f;
#pragma unroll
  for (int kk = 0; kk < 2; ++kk)
#pragma unroll
    for (int e = 0; e < 8; ++e) { const float f = (float)qf[kk][e]; q2 += f * f; }
  q2 += __shfl_xor(q2, 16);
  q2 += __shfl_xor(q2, 32);
  const float m_fix = sqrtf(q2 * kmax[nh]);
  float l_run = 0.f;
  f32x4 o[3] = {};
  for (int t = 0; t < 12; ++t) {
    const int s0 = t * 64;
    __syncthreads();
    {
      const int rbase = w * 8;
      gll(KVH + bk + (size_t)(s0 + rbase + (lane >> 3)) * 768 + scol, &Ks[rbase * 64]);
    }
    if (w < 6) {
      const int rbase = w * 8;
      gll(vt + (size_t)(rbase + (lane >> 3)) * 768 + s0 + scol, &Vs[rbase * 64]);
    }
    __syncthreads();
    f32x4 sc[4];
#pragma unroll
    for (int st = 0; st < 4; ++st) {
      f32x4 a = {};
#pragma unroll
      for (int kk = 0; kk < 2; ++kk) {
        const bf16x8 kf = *(const bf16x8*)&Ks[(st * 16 + li) * 64 + ((kk * 32 + gq * 8) ^ rsw)];
        a = __builtin_amdgcn_mfma_f32_16x16x32_bf16(kf, qf[kk], a, 0, 0, 0);
      }
      sc[st] = a;
    }
    if (t == 11) {
#pragma unroll
      for (int st = 0; st < 4; ++st)
#pragma unroll
        for (int r = 0; r < 4; ++r)
          if (st * 16 + gq * 4 + r >= 52) sc[st][r] = -1e30f;
    }
#pragma unroll
    for (int st = 0; st < 4; ++st)
#pragma unroll
      for (int r = 0; r < 4; ++r) {
        const float p = __builtin_amdgcn_exp2f(sc[st][r] - m_fix);
        sc[st][r] = p;
        l_run += p;
      }
#pragma unroll
    for (int st = 0; st < 4; ++st) {
      bf16x4 pk;
#pragma unroll
      for (int r = 0; r < 4; ++r) pk[r] = (__bf16)sc[st][r];
      *(bf16x4*)&Pw[li * 68 + st * 16 + gq * 4] = pk;
    }
#pragma unroll
    for (int kk = 0; kk < 2; ++kk) {
      const bf16x4 plo = *(const bf16x4*)&Pw[li * 68 + kk * 32 + gq * 8];
      const bf16x4 phi = *(const bf16x4*)&Pw[li * 68 + kk * 32 + gq * 8 + 4];
      bf16x8 ap;
#pragma unroll
      for (int e = 0; e < 4; ++e) { ap[e] = plo[e]; ap[e + 4] = phi[e]; }
#pragma unroll
      for (int df = 0; df < 3; ++df) {
        const bf16x8 bv = *(const bf16x8*)&Vs[(df * 16 + li) * 64 + ((kk * 32 + gq * 8) ^ rsw)];
        o[df] = __builtin_amdgcn_mfma_f32_16x16x32_bf16(ap, bv, o[df], 0, 0, 0);
      }
    }
  }
  l_run += __shfl_xor(l_run, 16);
  l_run += __shfl_xor(l_run, 32);
  const float inv = 1.f / l_run;
  float ir[4];
#pragma unroll
  for (int r = 0; r < 4; ++r) ir[r] = __shfl(inv, gq * 4 + r, 16);
#pragma unroll
  for (int df = 0; df < 3; ++df)
#pragma unroll
    for (int r = 0; r < 4; ++r)
      AO[bq + (size_t)(l0w + gq * 4 + r) * 384 + df * 16 + li] = (__bf16)(o[df][r] * ir[r]);
}

// ---------------- K7: LN1 over c of (loc + attn_proj); writes in place ----------------
__global__ __launch_bounds__(256) void k_ln1(const __bf16* Q,
    const __bf16* P, const float* g1, const float* b1, __bf16* S1) {
  const size_t row = (size_t)blockIdx.x * 4 + (threadIdx.x >> 6);
  const int lane = threadIdx.x & 63;
  const __bf16* q = Q + row * 384;
  const __bf16* p = P + row * 384;
  float v[6], s = 0.f;
#pragma unroll
  for (int e = 0; e < 6; ++e) {
    const int c = e * 64 + lane;
    v[e] = (float)q[c] + (float)p[c];
    s += v[e];
  }
  s = wave_sum(s);
  const float mean = s * (1.f / 384.f);
  float var = 0.f;
#pragma unroll
  for (int e = 0; e < 6; ++e) { const float d = v[e] - mean; var += d * d; }
  var = wave_sum(var) * (1.f / 384.f);
  const float rstd = rsqrtf(var + 1e-5f);
  __bf16* o = S1 + row * 384;
#pragma unroll
  for (int e = 0; e < 6; ++e) {
    const int c = e * 64 + lane;
    o[c] = (__bf16)(((v[e] - mean) * rstd) * g1[c] + b1[c]);
  }
}

// ---- K10: LN2 of (S1 + FF) -> transposed f32 store; fused glb-quadrant update ----
__global__ __launch_bounds__(256) void k_ln2(const __bf16* __restrict__ S1,
    const __bf16* __restrict__ FF, const float* __restrict__ g2,
    const float* __restrict__ b2, const float* __restrict__ x,
    float* __restrict__ out) {
  const int n = blockIdx.y, l0 = blockIdx.x * 64;
  const int tid = threadIdx.x, w = tid >> 6, lane = tid & 63;
  __shared__ __bf16 tile[64][390];
  for (int rr = 0; rr < 16; ++rr) {
    const int ll = w * 16 + rr;
    const size_t row = ((size_t)n * 9216 + l0 + ll) * 384;
    float v[6], s = 0.f;
#pragma unroll
    for (int e = 0; e < 6; ++e) {
      const int c = e * 64 + lane;
      v[e] = (float)S1[row + c] + (float)FF[row + c];
      s += v[e];
    }
    s = wave_sum(s);
    const float mean = s * (1.f / 384.f);
    float var = 0.f;
#pragma unroll
    for (int e = 0; e < 6; ++e) { const float d = v[e] - mean; var += d * d; }
    var = wave_sum(var) * (1.f / 384.f);
    const float rstd = rsqrtf(var + 1e-5f);
#pragma unroll
    for (int e = 0; e < 6; ++e) {
      const int c = e * 64 + lane;
      tile[ll][c] = (__bf16)(((v[e] - mean) * rstd) * g2[c] + b2[c]);
    }
  }
  __syncthreads();
  const int l = l0 + lane, i = l / 96, j = l % 96;
  const int a = n >> 1, b = n & 1;
  const bool doGlb = ((i | j) & 1) == 0;
  const int gl = (a * 48 + (i >> 1)) * 96 + b * 48 + (j >> 1);
  for (int it = 0; it < 96; ++it) {
    const int c = it * 4 + w;
    const float v = (float)tile[lane][c];
    out[((size_t)n * 384 + c) * 9216 + l0 + lane] = v;
    if (doGlb) {
      const size_t gidx = (size_t)(4 * 384 + c) * 9216 + gl;
      out[gidx] = x[gidx] + v;
    }
  }
}

extern "C" void kernel_launch(void* const* d_in, const int* in_sizes, int n_in,
                              void* d_out, int out_size, void* d_ws, size_t ws_size,
                              hipStream_t stream) {
  const float* x     = (const float*)d_in[0];
  const float* sal_w = (const float*)d_in[1];
  const float* sal_b = (const float*)d_in[2];
  const float* aiw   = (const float*)d_in[3];
  const float* aib   = (const float*)d_in[4];
  const float* aow   = (const float*)d_in[5];
  const float* aob   = (const float*)d_in[6];
  const float* w3    = (const float*)d_in[7];
  const float* b3    = (const float*)d_in[8];
  const float* w4    = (const float*)d_in[9];
  const float* b4    = (const float*)d_in[10];
  const float* g1    = (const float*)d_in[11];
  const float* be1   = (const float*)d_in[12];
  const float* g2    = (const float*)d_in[13];
  const float* be2   = (const float*)d_in[14];
  float* out = (float*)d_out;
  char* ws = (char*)d_ws;

  // ws layout (total 69,636,096 B)
  float*  tam  = (float*)(ws + 0);                //     36,864 B
  __bf16* aiwB = (__bf16*)(ws + 36864);           //  3,538,944 B
  __bf16* aowB = (__bf16*)(ws + 3575808);         //  1,179,648 B
  __bf16* w3B  = (__bf16*)(ws + 4755456);         //    589,824 B
  __bf16* w4B  = (__bf16*)(ws + 5345280);         //    589,824 B
  __bf16* KV   = (__bf16*)(ws + 5935104);         //  2,359,296 B (pools; later VTg)
  __bf16* KVH  = (__bf16*)(ws + 8294400);         //  4,718,592 B (K|V merged [4][768][768])
  __bf16* Q    = (__bf16*)(ws + 13012992);        // 28,311,552 B  loc_scaled -> S1 (in place)
  __bf16* QHb  = (__bf16*)(ws + 41324544);        // 28,311,552 B  qproj -> P -> FF
  __bf16* VTg = KV;               // V^T [32][48][768] reuses pools slot
  __bf16* AO  = (__bf16*)d_out;   // attn out [4][9216][384] bf16 (28.3 MB of 70.8)
  __bf16* HID = (__bf16*)d_out;   // FFN hidden 36864x768 bf16 (56.6 MB, AO dead by then)
  float* kmax = (float*)((char*)d_out + 70778368);  // last 512 B of d_out
  __bf16* P   = QHb;
  __bf16* S1  = Q;
  __bf16* FF  = QHb;

  const float qscale = 0.20823509f;  // (1/sqrt(48)) * log2(e)

  k_cvt4<<<2880, 256, 0, stream>>>(aiw, aow, w3, w4, aiwB, aowB, w3B, w4B, kmax);

  k_tam<<<144, 256, 0, stream>>>(x, sal_w, sal_b, tam);
  k_locscale<<<dim3(144, 4), 256, 0, stream>>>(x, tam, Q);
  k_pool<<<dim3(384, 4), 64, 0, stream>>>(x, KV);

  // merged K+V projection: KVH[768 s][768] = K | V
  k_gemm<0><<<dim3(6, 6, 4), 256, 0, stream>>>(KV, aiwB + 384 * 384, aib + 384, KVH,
      384, 768L * 384, 1152L * 384, 1152L, 768L * 768, 1.f);
  // Q projection (pre-scaled for log2-domain softmax), 256-row tiles
  k_gemm256<0><<<dim3(3, 36, 4), 512, 0, stream>>>(Q, aiwB, aib, QHb,
      384, 9216L * 384, 1152L * 384, 1152L, 9216L * 384, qscale);

  // V transpose + kmax (fused)
  k_vt<<<dim3(3, 32), 256, 0, stream>>>(KVH, VTg, kmax);

  k_attn<<<dim3(72, 32), 512, 0, stream>>>(QHb, KVH, VTg, kmax, AO);

  // out-projection: AO x aow^T -> P (QHb region; qproj dead), 256-row tiles
  k_gemm256<0><<<dim3(3, 36, 4), 512, 0, stream>>>(AO, aowB, aob, P,
      384, 9216L * 384, 384L * 384, 384L, 9216L * 384, 1.f);

  // LN1 in place into Q region
  k_ln1<<<9216, 256, 0, stream>>>(Q, P, g1, be1, S1);

  // FFN single pass: HID (d_out, AO dead) <- GELU(S1 w3^T); FF (QHb) <- HID w4^T
  k_gemm256<1><<<dim3(6, 144, 1), 512, 0, stream>>>(S1, w3B, b3, HID,
      384, 0, 0, 0, 0, 1.f);
  k_gemm256<0><<<dim3(3, 144, 1), 512, 0, stream>>>(HID, w4B, b4, FF,
      768, 0, 0, 0, 0, 1.f);

  // LN2 + transposed f32 store + fused glb update
  k_ln2<<<dim3(144, 4), 256, 0, stream>>>(S1, FF, g2, be2, x, out);
}